// Round 1
// baseline (7113.651 us; speedup 1.0000x reference)
//
#include <hip/hip_runtime.h>
#include <float.h>
#include <math.h>

#define D 1024
#define NF 64
#define MDICT 16384
#define NH 16
#define DH 64
#define TT 2048
#define ROWS 4096   // B*T
#define DFF 4096

// d_out layout (floats)
#define OUT_X     0LL
#define OUT_ATTN  4194304LL
#define OUT_FS    138412032LL
#define OUT_SPARS 138674176LL
#define OUT_E1    138674177LL
#define OUT_E2    138674178LL

// ---------------- block reduce helpers (blockDim == 256) ----------------
__device__ inline float blk_sum(float v) {
    __shared__ float sb[4];
    int lane = threadIdx.x & 63, w = threadIdx.x >> 6;
#pragma unroll
    for (int o = 32; o; o >>= 1) v += __shfl_down(v, o);
    if (lane == 0) sb[w] = v;
    __syncthreads();
    float s = sb[0] + sb[1] + sb[2] + sb[3];
    __syncthreads();
    return s;
}

__device__ inline float blk_max(float v) {
    __shared__ float sm[4];
    int lane = threadIdx.x & 63, w = threadIdx.x >> 6;
#pragma unroll
    for (int o = 32; o; o >>= 1) v = fmaxf(v, __shfl_down(v, o));
    if (lane == 0) sm[w] = v;
    __syncthreads();
    float s = fmaxf(fmaxf(sm[0], sm[1]), fmaxf(sm[2], sm[3]));
    __syncthreads();
    return s;
}

// ---------------- generic tiled fp32 GEMM: C = alpha * A @ B^T (+ add) ----
// A: [R,K] row-major lda; B: [N,K] row-major ldb; C: [R,N] ldc.
// Grid: (N/128, R/128, batches). batch z decomposed zo=z/batchH, zi=z%batchH.
__global__ __launch_bounds__(256) void gemm_abt(
    const float* __restrict__ Ab, const float* __restrict__ Bb,
    float* __restrict__ Cb, const float* __restrict__ addCb,
    int K, int lda, int ldb, int ldc, float alpha, int batchH,
    long long aOut, long long aIn, long long bOut, long long bIn,
    long long cOut, long long cIn)
{
    int z = blockIdx.z;
    int zo = z / batchH, zi = z - zo * batchH;
    const float* A = Ab + zo * aOut + zi * aIn;
    const float* B = Bb + zo * bOut + zi * bIn;
    float* C = Cb + zo * cOut + zi * cIn;
    const float* addC = addCb ? (addCb + zo * cOut + zi * cIn) : nullptr;

    __shared__ float As[16][132];
    __shared__ float Bs[16][132];
    int tid = threadIdx.x;
    int tx = tid & 15, ty = tid >> 4;
    long long r0 = (long long)blockIdx.y * 128;
    long long c0 = (long long)blockIdx.x * 128;
    float acc[8][8] = {{0.f}};

    for (int k0 = 0; k0 < K; k0 += 16) {
        __syncthreads();
#pragma unroll
        for (int s = 0; s < 8; s++) {
            int l = tid + s * 256;
            int m = l >> 4, kk = l & 15;
            As[kk][m] = A[(r0 + m) * (long long)lda + k0 + kk];
            Bs[kk][m] = B[(c0 + m) * (long long)ldb + k0 + kk];
        }
        __syncthreads();
#pragma unroll
        for (int kk = 0; kk < 16; kk++) {
            float a[8], b[8];
#pragma unroll
            for (int i = 0; i < 8; i++) a[i] = As[kk][ty * 8 + i];
#pragma unroll
            for (int j = 0; j < 8; j++) b[j] = Bs[kk][tx * 8 + j];
#pragma unroll
            for (int i = 0; i < 8; i++)
#pragma unroll
                for (int j = 0; j < 8; j++)
                    acc[i][j] += a[i] * b[j];
        }
    }
#pragma unroll
    for (int i = 0; i < 8; i++) {
        long long row = r0 + ty * 8 + i;
#pragma unroll
        for (int j = 0; j < 8; j++) {
            long long col = c0 + tx * 8 + j;
            long long idx = row * ldc + col;
            float v = alpha * acc[i][j];
            if (addC) v += addC[idx];
            C[idx] = v;
        }
    }
}

// ---------------- family gate: logits + softmax ----------------
__global__ __launch_bounds__(64) void family_kernel(
    const float* __restrict__ x, const float* __restrict__ fgw,
    float* __restrict__ fs_out)
{
    __shared__ float xs[D];
    int r = blockIdx.x, f = threadIdx.x;
    const float4* x4 = (const float4*)(x + (long long)r * D);
    float4* xs4 = (float4*)xs;
#pragma unroll
    for (int i = 0; i < 4; i++) xs4[f + 64 * i] = x4[f + 64 * i];
    __syncthreads();
    const float4* w4 = (const float4*)(fgw + (long long)f * D);
    float acc = 0.f;
#pragma unroll 8
    for (int d = 0; d < D / 4; d++) {
        float4 w = w4[d];
        float4 xv = xs4[d];
        acc += w.x * xv.x + w.y * xv.y + w.z * xv.z + w.w * xv.w;
    }
    float mx = acc;
#pragma unroll
    for (int o = 32; o; o >>= 1) mx = fmaxf(mx, __shfl_xor(mx, o));
    float e = __expf(acc - mx);
    float s = e;
#pragma unroll
    for (int o = 32; o; o >>= 1) s += __shfl_xor(s, o);
    fs_out[(long long)r * NF + f] = e / s;
}

// ---------------- basis = fs @ proto ; resid = x - basis ----------------
__global__ __launch_bounds__(256) void basis_kernel(
    const float* __restrict__ x, const float* __restrict__ fs,
    const float* __restrict__ proto, float* __restrict__ basis,
    float* __restrict__ resid)
{
    __shared__ float Ss[NF];
    int r = blockIdx.x, tid = threadIdx.x;
    if (tid < NF) Ss[tid] = fs[(long long)r * NF + tid];
    __syncthreads();
    float4 acc = {0.f, 0.f, 0.f, 0.f};
    const float4* p4 = (const float4*)proto;
#pragma unroll 8
    for (int k = 0; k < NF; k++) {
        float s = Ss[k];
        float4 p = p4[k * (D / 4) + tid];
        acc.x += s * p.x; acc.y += s * p.y; acc.z += s * p.z; acc.w += s * p.w;
    }
    long long base = (long long)r * (D / 4) + tid;
    float4 xv = ((const float4*)x)[base];
    ((float4*)basis)[base] = acc;
    float4 rv = {xv.x - acc.x, xv.y - acc.y, xv.z - acc.z, xv.w - acc.w};
    ((float4*)resid)[base] = rv;
}

// ---------------- top-8 per row of coeffs [4096, 16384] ----------------
__device__ inline void ins8(float v, int idx, float* vs, int* is) {
    if (v <= vs[7]) return;
    vs[7] = v; is[7] = idx;
#pragma unroll
    for (int j = 7; j > 0; j--) {
        if (vs[j] > vs[j - 1]) {
            float tv = vs[j]; vs[j] = vs[j - 1]; vs[j - 1] = tv;
            int ti = is[j]; is[j] = is[j - 1]; is[j - 1] = ti;
        }
    }
}

__global__ __launch_bounds__(256) void topk_kernel(
    const float* __restrict__ coeffs, float* __restrict__ tkv,
    int* __restrict__ tki, float* __restrict__ spars_acc)
{
    __shared__ float sv[2624];
    __shared__ int   si[2624];
    int r = blockIdx.x, tid = threadIdx.x;
    const float* row = coeffs + (long long)r * MDICT;
    float vs[8]; int is[8];
#pragma unroll
    for (int j = 0; j < 8; j++) { vs[j] = -FLT_MAX; is[j] = -1; }
    for (int s = 0; s < MDICT / 256; s++) {
        int col = s * 256 + tid;
        ins8(row[col], col, vs, is);
    }
#pragma unroll
    for (int j = 0; j < 8; j++) { sv[tid * 8 + j] = vs[j]; si[tid * 8 + j] = is[j]; }
    __syncthreads();
    if (tid < 64) {
#pragma unroll
        for (int j = 0; j < 8; j++) { vs[j] = -FLT_MAX; is[j] = -1; }
        for (int e = tid * 32; e < tid * 32 + 32; e++) ins8(sv[e], si[e], vs, is);
#pragma unroll
        for (int j = 0; j < 8; j++) { sv[2048 + tid * 8 + j] = vs[j]; si[2048 + tid * 8 + j] = is[j]; }
    }
    __syncthreads();
    if (tid < 8) {
#pragma unroll
        for (int j = 0; j < 8; j++) { vs[j] = -FLT_MAX; is[j] = -1; }
        for (int e = 2048 + tid * 64; e < 2048 + tid * 64 + 64; e++) ins8(sv[e], si[e], vs, is);
#pragma unroll
        for (int j = 0; j < 8; j++) { sv[2560 + tid * 8 + j] = vs[j]; si[2560 + tid * 8 + j] = is[j]; }
    }
    __syncthreads();
    if (tid == 0) {
#pragma unroll
        for (int j = 0; j < 8; j++) { vs[j] = -FLT_MAX; is[j] = -1; }
        for (int e = 2560; e < 2624; e++) ins8(sv[e], si[e], vs, is);
        float s = 0.f;
#pragma unroll
        for (int j = 0; j < 8; j++) {
            tkv[r * 8 + j] = vs[j];
            tki[r * 8 + j] = is[j];
            s += fabsf(vs[j]);
        }
        atomicAdd(spars_acc, s);
    }
}

// ---------------- x_rec = basis + offset + bias ; norm1 -> normed --------
__global__ __launch_bounds__(256) void xrec_norm_kernel(
    const float* __restrict__ basis, const float* __restrict__ dictw,
    const float* __restrict__ bias, const float* __restrict__ nw,
    const float* __restrict__ tkv, const int* __restrict__ tki,
    float* __restrict__ normed, float* __restrict__ e_acc)
{
    int r = blockIdx.x, tid = threadIdx.x;
    float vals[8]; int idxs[8];
#pragma unroll
    for (int j = 0; j < 8; j++) { vals[j] = tkv[r * 8 + j]; idxs[j] = tki[r * 8 + j]; }
    long long base = (long long)r * (D / 4) + tid;
    float4 acc = ((const float4*)basis)[base];
    float4 bv = ((const float4*)bias)[tid];
    acc.x += bv.x; acc.y += bv.y; acc.z += bv.z; acc.w += bv.w;
#pragma unroll
    for (int j = 0; j < 8; j++) {
        float4 dv = ((const float4*)dictw)[(long long)idxs[j] * (D / 4) + tid];
        float v = vals[j];
        acc.x += v * dv.x; acc.y += v * dv.y; acc.z += v * dv.z; acc.w += v * dv.w;
    }
    float ss = acc.x * acc.x + acc.y * acc.y + acc.z * acc.z + acc.w * acc.w;
    float tot = blk_sum(ss);
    float rms = sqrtf(tot / (float)D + 1e-6f);
    if (tid == 0) atomicAdd(e_acc, rms);
    float inv = 1.f / rms;
    float4 wv = ((const float4*)nw)[tid];
    float4 o = {acc.x * wv.x * inv, acc.y * wv.y * inv, acc.z * wv.z * inv, acc.w * wv.w * inv};
    ((float4*)normed)[base] = o;
}

// ---------------- plain rmsnorm (norm2) ----------------
__global__ __launch_bounds__(256) void rmsnorm_kernel(
    const float* __restrict__ xin, const float* __restrict__ nw,
    float* __restrict__ xout, float* __restrict__ e_acc)
{
    int r = blockIdx.x, tid = threadIdx.x;
    long long base = (long long)r * (D / 4) + tid;
    float4 v = ((const float4*)xin)[base];
    float ss = v.x * v.x + v.y * v.y + v.z * v.z + v.w * v.w;
    float tot = blk_sum(ss);
    float rms = sqrtf(tot / (float)D + 1e-6f);
    if (tid == 0) atomicAdd(e_acc, rms);
    float inv = 1.f / rms;
    float4 wv = ((const float4*)nw)[tid];
    float4 o = {v.x * wv.x * inv, v.y * wv.y * inv, v.z * wv.z * inv, v.w * wv.w * inv};
    ((float4*)xout)[base] = o;
}

// ---------------- k_mod[b,h,t,e] = sum_d k[b,h,t,d] * rel[h,d,e] ----------
__global__ __launch_bounds__(256) void kmod_kernel(
    const float* __restrict__ kbuf, const float* __restrict__ rel,
    float* __restrict__ kmod)
{
    __shared__ float Rs[64 * 64];
    int z = blockIdx.y;
    int b = z >> 4, h = z & 15;
    int tid = threadIdx.x;
    const float4* r4 = (const float4*)(rel + (long long)h * 4096);
    float4* Rs4 = (float4*)Rs;
#pragma unroll
    for (int i = 0; i < 4; i++) Rs4[tid + 256 * i] = r4[tid + 256 * i];
    __syncthreads();
    int e = tid & 63, tl = tid >> 6;
    int t = blockIdx.x * 4 + tl;
    const float* krow = kbuf + ((long long)(b * TT + t)) * D + h * DH;
    float acc = 0.f;
#pragma unroll 8
    for (int d = 0; d < 64; d++) acc += krow[d] * Rs[d * 64 + e];
    kmod[(long long)z * (TT * DH) + t * 64 + e] = acc;
}

// ---------------- softmax over rows of attn (width 2048) ------------------
__global__ __launch_bounds__(256) void softmax_kernel(float* __restrict__ attn)
{
    long long row = blockIdx.x;
    float4* p4 = (float4*)(attn + row * TT);
    int tid = threadIdx.x;
    float4 v0 = p4[tid], v1 = p4[tid + 256];
    float mx = fmaxf(fmaxf(fmaxf(v0.x, v0.y), fmaxf(v0.z, v0.w)),
                     fmaxf(fmaxf(v1.x, v1.y), fmaxf(v1.z, v1.w)));
    mx = blk_max(mx);
    v0.x = __expf(v0.x - mx); v0.y = __expf(v0.y - mx);
    v0.z = __expf(v0.z - mx); v0.w = __expf(v0.w - mx);
    v1.x = __expf(v1.x - mx); v1.y = __expf(v1.y - mx);
    v1.z = __expf(v1.z - mx); v1.w = __expf(v1.w - mx);
    float s = v0.x + v0.y + v0.z + v0.w + v1.x + v1.y + v1.z + v1.w;
    s = blk_sum(s);
    float inv = 1.f / s;
    v0.x *= inv; v0.y *= inv; v0.z *= inv; v0.w *= inv;
    v1.x *= inv; v1.y *= inv; v1.z *= inv; v1.w *= inv;
    p4[tid] = v0; p4[tid + 256] = v1;
}

// ---------------- ctx = attn @ v  (per b,h; output in flat [4096,1024]) ---
__global__ __launch_bounds__(256) void ctx_kernel(
    const float* __restrict__ attn, const float* __restrict__ vbuf,
    float* __restrict__ ctx)
{
    __shared__ float As[32][64];
    __shared__ float Vs[64][64];
    int z = blockIdx.y;
    int b = z >> 4, h = z & 15;
    int tb = blockIdx.x;
    int tid = threadIdx.x;
    int dh = tid & 63, w = tid >> 6;
    const float* arow = attn + (long long)z * TT * TT + (long long)tb * 32 * TT;
    float acc[8] = {0.f, 0.f, 0.f, 0.f, 0.f, 0.f, 0.f, 0.f};
    for (int kb = 0; kb < TT; kb += 64) {
        __syncthreads();
#pragma unroll
        for (int s = 0; s < 8; s++) {
            int l = tid + s * 256;
            As[l >> 6][l & 63] = arow[(long long)(l >> 6) * TT + kb + (l & 63)];
        }
#pragma unroll
        for (int s = 0; s < 16; s++) {
            int l = tid + s * 256;
            Vs[l >> 6][l & 63] = vbuf[((long long)(b * TT + kb + (l >> 6))) * D + h * DH + (l & 63)];
        }
        __syncthreads();
#pragma unroll
        for (int kk = 0; kk < 64; kk += 4) {
            float u0 = Vs[kk][dh], u1 = Vs[kk + 1][dh], u2 = Vs[kk + 2][dh], u3 = Vs[kk + 3][dh];
#pragma unroll
            for (int j = 0; j < 8; j++) {
                float4 a = *(const float4*)&As[w * 8 + j][kk];
                acc[j] += a.x * u0 + a.y * u1 + a.z * u2 + a.w * u3;
            }
        }
    }
#pragma unroll
    for (int j = 0; j < 8; j++) {
        int t = tb * 32 + w * 8 + j;
        ctx[((long long)(b * TT + t)) * D + h * DH + dh] = acc[j];
    }
}

// ---------------- h = sigmoid(g) * silu(u), in place into g ---------------
__global__ __launch_bounds__(256) void gateup_kernel(
    float* __restrict__ g, const float* __restrict__ u, long long n4)
{
    long long i = (long long)blockIdx.x * 256 + threadIdx.x;
    long long stride = (long long)gridDim.x * 256;
    for (; i < n4; i += stride) {
        float4 gv = ((float4*)g)[i];
        float4 uv = ((const float4*)u)[i];
        gv.x = (1.f / (1.f + __expf(-gv.x))) * uv.x * (1.f / (1.f + __expf(-uv.x)));
        gv.y = (1.f / (1.f + __expf(-gv.y))) * uv.y * (1.f / (1.f + __expf(-uv.y)));
        gv.z = (1.f / (1.f + __expf(-gv.z))) * uv.z * (1.f / (1.f + __expf(-uv.z)));
        gv.w = (1.f / (1.f + __expf(-gv.w))) * uv.w * (1.f / (1.f + __expf(-uv.w)));
        ((float4*)g)[i] = gv;
    }
}

// ---------------- finalize scalars ----------------
__global__ void finalize_kernel(const float* __restrict__ scal, float* __restrict__ out)
{
    out[OUT_SPARS] = scal[0] / (float)((double)ROWS * (double)MDICT);
    out[OUT_E1] = scal[1] / (float)ROWS;
    out[OUT_E2] = scal[2] / (float)ROWS;
}

extern "C" void kernel_launch(void* const* d_in, const int* in_sizes, int n_in,
                              void* d_out, int out_size, void* d_ws, size_t ws_size,
                              hipStream_t stream) {
    const float* x     = (const float*)d_in[0];
    const float* proto = (const float*)d_in[2];
    const float* fgw   = (const float*)d_in[3];
    const float* dictw = (const float*)d_in[4];
    const float* encw  = (const float*)d_in[5];
    const float* wq    = (const float*)d_in[6];
    const float* wk    = (const float*)d_in[7];
    const float* wv    = (const float*)d_in[8];
    const float* wo    = (const float*)d_in[9];
    const float* rel   = (const float*)d_in[10];
    const float* gatew = (const float*)d_in[11];
    const float* upw   = (const float*)d_in[12];
    const float* downw = (const float*)d_in[13];
    const float* n1w   = (const float*)d_in[14];
    const float* n2w   = (const float*)d_in[15];
    const float* bias  = (const float*)d_in[16];
    float* out = (float*)d_out;
    float* ws  = (float*)d_ws;

    // ws arena (floats). Reuse: ctx=resid, xmid=basis, normed2=normed,
    // gate spans [qb .. kmod+] (16.7M floats contiguous).
    float* basis  = ws + 0;
    float* resid  = ws + 4194304;
    float* normed = ws + 8388608;
    float* qb     = ws + 12582912;
    float* kb     = ws + 16777216;
    float* vb     = ws + 20971520;
    float* kmod   = ws + 25165824;
    float* upb    = ws + 29360128;   // 16777216 floats
    float* tkv    = ws + 46137344;
    int*   tki    = (int*)(ws + 46170112);
    float* scal   = ws + 46202880;   // [sparsity_sum, e1_sum, e2_sum]
    float* ctx = resid;
    float* xmid = basis;
    float* normed2 = normed;
    float* gateb = qb;

    float* fs   = out + OUT_FS;
    float* attn = out + OUT_ATTN;
    float* coeffs = attn;            // scratch until attn scores written

    hipMemsetAsync(scal, 0, 3 * sizeof(float), stream);

    family_kernel<<<ROWS, 64, 0, stream>>>(x, fgw, fs);
    basis_kernel<<<ROWS, 256, 0, stream>>>(x, fs, proto, basis, resid);
    // coeffs[4096,16384] = resid @ enc_w^T
    gemm_abt<<<dim3(128, 32, 1), 256, 0, stream>>>(
        resid, encw, coeffs, nullptr, D, D, D, MDICT, 1.f, 1, 0, 0, 0, 0, 0, 0);
    topk_kernel<<<ROWS, 256, 0, stream>>>(coeffs, tkv, tki, scal + 0);
    xrec_norm_kernel<<<ROWS, 256, 0, stream>>>(basis, dictw, bias, n1w, tkv, tki, normed, scal + 1);
    // q,k,v [4096,1024]
    gemm_abt<<<dim3(8, 32, 1), 256, 0, stream>>>(
        normed, wq, qb, nullptr, D, D, D, D, 1.f, 1, 0, 0, 0, 0, 0, 0);
    gemm_abt<<<dim3(8, 32, 1), 256, 0, stream>>>(
        normed, wk, kb, nullptr, D, D, D, D, 1.f, 1, 0, 0, 0, 0, 0, 0);
    gemm_abt<<<dim3(8, 32, 1), 256, 0, stream>>>(
        normed, wv, vb, nullptr, D, D, D, D, 1.f, 1, 0, 0, 0, 0, 0, 0);
    kmod_kernel<<<dim3(TT / 4, 32), 256, 0, stream>>>(kb, rel, kmod);
    // scores: per (b,h): q[2048,64] @ kmod[2048,64]^T * 0.125 -> attn
    gemm_abt<<<dim3(16, 16, 32), 256, 0, stream>>>(
        qb, kmod, attn, nullptr, DH, D, DH, TT, 0.125f, NH,
        (long long)TT * D, 64LL,
        (long long)NH * TT * DH, (long long)TT * DH,
        (long long)NH * TT * TT, (long long)TT * TT);
    softmax_kernel<<<32 * TT, 256, 0, stream>>>(attn);
    ctx_kernel<<<dim3(TT / 32, 32), 256, 0, stream>>>(attn, vb, ctx);
    // xmid = ctx @ wo^T + x
    gemm_abt<<<dim3(8, 32, 1), 256, 0, stream>>>(
        ctx, wo, xmid, x, D, D, D, D, 1.f, 1, 0, 0, 0, 0, 0, 0);
    rmsnorm_kernel<<<ROWS, 256, 0, stream>>>(xmid, n2w, normed2, scal + 2);
    gemm_abt<<<dim3(32, 32, 1), 256, 0, stream>>>(
        normed2, gatew, gateb, nullptr, D, D, D, DFF, 1.f, 1, 0, 0, 0, 0, 0, 0);
    gemm_abt<<<dim3(32, 32, 1), 256, 0, stream>>>(
        normed2, upw, upb, nullptr, D, D, D, DFF, 1.f, 1, 0, 0, 0, 0, 0, 0);
    gateup_kernel<<<4096, 256, 0, stream>>>(gateb, upb, (long long)ROWS * DFF / 4);
    // out_x = h @ down^T + xmid
    gemm_abt<<<dim3(8, 32, 1), 256, 0, stream>>>(
        gateb, downw, out + OUT_X, xmid, DFF, DFF, DFF, D, 1.f, 1, 0, 0, 0, 0, 0, 0);
    finalize_kernel<<<1, 1, 0, stream>>>(scal, out);
}

// Round 2
// 2289.888 us; speedup vs baseline: 3.1065x; 3.1065x over previous
//
#include <hip/hip_runtime.h>
#include <float.h>
#include <math.h>

#define D 1024
#define NF 64
#define MDICT 16384
#define NH 16
#define DH 64
#define TT 2048
#define ROWS 4096   // B*T
#define DFF 4096

// d_out layout (floats)
#define OUT_X     0LL
#define OUT_ATTN  4194304LL
#define OUT_FS    138412032LL
#define OUT_SPARS 138674176LL
#define OUT_E1    138674177LL
#define OUT_E2    138674178LL

typedef __attribute__((ext_vector_type(8))) short short8;
typedef __attribute__((ext_vector_type(4))) float f32x4;

__device__ inline unsigned short f2bf(float f) {
    unsigned int u = __float_as_uint(f);
    u = u + 0x7FFFu + ((u >> 16) & 1u);   // round-to-nearest-even (finite vals)
    return (unsigned short)(u >> 16);
}
__device__ inline float bf2f(unsigned int s) {
    return __uint_as_float(s << 16);
}

// ---------------- block reduce helpers (blockDim == 256) ----------------
__device__ inline float blk_sum(float v) {
    __shared__ float sb[4];
    int lane = threadIdx.x & 63, w = threadIdx.x >> 6;
#pragma unroll
    for (int o = 32; o; o >>= 1) v += __shfl_down(v, o);
    if (lane == 0) sb[w] = v;
    __syncthreads();
    float s = sb[0] + sb[1] + sb[2] + sb[3];
    __syncthreads();
    return s;
}

__device__ inline float blk_max(float v) {
    __shared__ float sm[4];
    int lane = threadIdx.x & 63, w = threadIdx.x >> 6;
#pragma unroll
    for (int o = 32; o; o >>= 1) v = fmaxf(v, __shfl_down(v, o));
    if (lane == 0) sm[w] = v;
    __syncthreads();
    float s = fmaxf(fmaxf(sm[0], sm[1]), fmaxf(sm[2], sm[3]));
    __syncthreads();
    return s;
}

// =======================================================================
// bf16 MFMA GEMM: C = alpha * A @ B^T (+ addC).  A:[M,K] B:[N,K] row-major.
// BK=32, 256 threads = 4 waves in 2x2; wave tile (BM/2)x(BN/2) of 16x16x32
// MFMAs. B staged via global_load_lds (16B); A likewise unless ACONV, in
// which case A is fp32 in global and is converted in VGPRs + ds_write_b128.
// Grid: (N/BN, M/BM, batches); z -> zo=z/batchH, zi=z%batchH.
// =======================================================================
template<int BM, int BN, bool OBF, bool ACONV>
__global__ __launch_bounds__(256) void gemm_mfma(
    const void* __restrict__ Abv, const unsigned short* __restrict__ Bb,
    void* __restrict__ Cbv, const float* __restrict__ addCb,
    int K, int lda, int ldb, int ldc, float alpha, int batchH,
    long long aOut, long long aIn, long long bOut, long long bIn,
    long long cOut, long long cIn)
{
    int z = blockIdx.z;
    int zo = z / batchH, zi = z - zo * batchH;
    long long aoff = zo * aOut + zi * aIn;
    const unsigned short* B = Bb + zo * bOut + zi * bIn;
    long long cbase = zo * cOut + zi * cIn;
    const float* addC = addCb ? (addCb + cbase) : nullptr;

    __shared__ __align__(16) unsigned short As[BM * 32];
    __shared__ __align__(16) unsigned short Bs[BN * 32];

    int tid = threadIdx.x;
    int lane = tid & 63, wave = tid >> 6;
    int wr = wave >> 1, wc = wave & 1;
    long long r0 = (long long)blockIdx.y * BM;
    long long c0 = (long long)blockIdx.x * BN;

    constexpr int TI = BM / 32;   // row tiles per wave
    constexpr int TJ = BN / 32;   // col tiles per wave
    constexpr int RA = BM * 4 / 256;
    constexpr int RB = BN * 4 / 256;

    f32x4 acc[TI][TJ] = {};
    int lm = lane & 15;
    int kq = (lane >> 4) * 8;

    for (int k0 = 0; k0 < K; k0 += 32) {
        __syncthreads();
        // ---- stage B (bf16, global->LDS direct) ----
#pragma unroll
        for (int r = 0; r < RB; r++) {
            int q = r * 256 + tid;
            const unsigned short* gp = B + (c0 + (q >> 2)) * (long long)ldb + k0 + (q & 3) * 8;
            unsigned short* lp = Bs + (r * 256 + (tid & 192)) * 8;  // wave-uniform base
            __builtin_amdgcn_global_load_lds(
                (const __attribute__((address_space(1))) void*)gp,
                (__attribute__((address_space(3))) void*)lp, 16, 0, 0);
        }
        // ---- stage A ----
        if (ACONV) {
            const float* A = (const float*)Abv + aoff;
#pragma unroll
            for (int r = 0; r < RA; r++) {
                int q = r * 256 + tid;
                const float* gp = A + (r0 + (q >> 2)) * (long long)lda + k0 + (q & 3) * 8;
                float4 v0 = *(const float4*)gp;
                float4 v1 = *(const float4*)(gp + 4);
                short8 f;
                f[0] = (short)f2bf(v0.x); f[1] = (short)f2bf(v0.y);
                f[2] = (short)f2bf(v0.z); f[3] = (short)f2bf(v0.w);
                f[4] = (short)f2bf(v1.x); f[5] = (short)f2bf(v1.y);
                f[6] = (short)f2bf(v1.z); f[7] = (short)f2bf(v1.w);
                *(short8*)&As[q * 8] = f;
            }
        } else {
            const unsigned short* A = (const unsigned short*)Abv + aoff;
#pragma unroll
            for (int r = 0; r < RA; r++) {
                int q = r * 256 + tid;
                const unsigned short* gp = A + (r0 + (q >> 2)) * (long long)lda + k0 + (q & 3) * 8;
                unsigned short* lp = As + (r * 256 + (tid & 192)) * 8;
                __builtin_amdgcn_global_load_lds(
                    (const __attribute__((address_space(1))) void*)gp,
                    (__attribute__((address_space(3))) void*)lp, 16, 0, 0);
            }
        }
        __syncthreads();
        // ---- fragments + MFMA ----
        short8 af[TI], bfr[TJ];
#pragma unroll
        for (int i = 0; i < TI; i++)
            af[i] = *(const short8*)&As[(wr * (BM / 2) + i * 16 + lm) * 32 + kq];
#pragma unroll
        for (int j = 0; j < TJ; j++)
            bfr[j] = *(const short8*)&Bs[(wc * (BN / 2) + j * 16 + lm) * 32 + kq];
#pragma unroll
        for (int i = 0; i < TI; i++)
#pragma unroll
            for (int j = 0; j < TJ; j++)
                acc[i][j] = __builtin_amdgcn_mfma_f32_16x16x32_bf16(af[i], bfr[j], acc[i][j], 0, 0, 0);
    }

    // ---- epilogue: C/D layout col=lane&15, row=(lane>>4)*4+reg ----
#pragma unroll
    for (int i = 0; i < TI; i++) {
#pragma unroll
        for (int r = 0; r < 4; r++) {
            long long row = r0 + wr * (BM / 2) + i * 16 + (lane >> 4) * 4 + r;
#pragma unroll
            for (int j = 0; j < TJ; j++) {
                long long col = c0 + wc * (BN / 2) + j * 16 + lm;
                long long idx = row * (long long)ldc + col;
                float v = alpha * acc[i][j][r];
                if (addC) v += addC[idx];
                if (OBF) ((unsigned short*)Cbv)[cbase + idx] = f2bf(v);
                else     ((float*)Cbv)[cbase + idx] = v;
            }
        }
    }
}

// ---------------- fp32 -> bf16 convert (grid-stride, 4/thread) -----------
__global__ __launch_bounds__(256) void cvt_bf16_kernel(
    const float* __restrict__ in, unsigned short* __restrict__ out, long long n4)
{
    long long i = (long long)blockIdx.x * 256 + threadIdx.x;
    long long stride = (long long)gridDim.x * 256;
    for (; i < n4; i += stride) {
        float4 v = ((const float4*)in)[i];
        uint2 p;
        p.x = (unsigned)f2bf(v.x) | ((unsigned)f2bf(v.y) << 16);
        p.y = (unsigned)f2bf(v.z) | ((unsigned)f2bf(v.w) << 16);
        ((uint2*)out)[i] = p;
    }
}

// ---------------- family gate: logits + softmax ----------------
__global__ __launch_bounds__(64) void family_kernel(
    const float* __restrict__ x, const float* __restrict__ fgw,
    float* __restrict__ fs_out)
{
    __shared__ float xs[D];
    int r = blockIdx.x, f = threadIdx.x;
    const float4* x4 = (const float4*)(x + (long long)r * D);
    float4* xs4 = (float4*)xs;
#pragma unroll
    for (int i = 0; i < 4; i++) xs4[f + 64 * i] = x4[f + 64 * i];
    __syncthreads();
    const float4* w4 = (const float4*)(fgw + (long long)f * D);
    float acc = 0.f;
#pragma unroll 8
    for (int d = 0; d < D / 4; d++) {
        float4 w = w4[d];
        float4 xv = xs4[d];
        acc += w.x * xv.x + w.y * xv.y + w.z * xv.z + w.w * xv.w;
    }
    float mx = acc;
#pragma unroll
    for (int o = 32; o; o >>= 1) mx = fmaxf(mx, __shfl_xor(mx, o));
    float e = __expf(acc - mx);
    float s = e;
#pragma unroll
    for (int o = 32; o; o >>= 1) s += __shfl_xor(s, o);
    fs_out[(long long)r * NF + f] = e / s;
}

// ------- basis = fs @ proto (fp32 out) ; resid = x - basis (bf16 out) ----
__global__ __launch_bounds__(256) void basis_kernel(
    const float* __restrict__ x, const float* __restrict__ fs,
    const float* __restrict__ proto, float* __restrict__ basis,
    unsigned short* __restrict__ resid_bf)
{
    __shared__ float Ss[NF];
    int r = blockIdx.x, tid = threadIdx.x;
    if (tid < NF) Ss[tid] = fs[(long long)r * NF + tid];
    __syncthreads();
    float4 acc = {0.f, 0.f, 0.f, 0.f};
    const float4* p4 = (const float4*)proto;
#pragma unroll 8
    for (int k = 0; k < NF; k++) {
        float s = Ss[k];
        float4 p = p4[k * (D / 4) + tid];
        acc.x += s * p.x; acc.y += s * p.y; acc.z += s * p.z; acc.w += s * p.w;
    }
    long long base = (long long)r * (D / 4) + tid;
    float4 xv = ((const float4*)x)[base];
    ((float4*)basis)[base] = acc;
    uint2 rp;
    rp.x = (unsigned)f2bf(xv.x - acc.x) | ((unsigned)f2bf(xv.y - acc.y) << 16);
    rp.y = (unsigned)f2bf(xv.z - acc.z) | ((unsigned)f2bf(xv.w - acc.w) << 16);
    ((uint2*)resid_bf)[base] = rp;
}

// ---------------- top-8 per row of coeffs [4096, 16384] ----------------
__device__ inline void ins8(float v, int idx, float* vs, int* is) {
    if (v <= vs[7]) return;
    vs[7] = v; is[7] = idx;
#pragma unroll
    for (int j = 7; j > 0; j--) {
        if (vs[j] > vs[j - 1]) {
            float tv = vs[j]; vs[j] = vs[j - 1]; vs[j - 1] = tv;
            int ti = is[j]; is[j] = is[j - 1]; is[j - 1] = ti;
        }
    }
}

__global__ __launch_bounds__(256) void topk_kernel(
    const float* __restrict__ coeffs, float* __restrict__ tkv,
    int* __restrict__ tki, float* __restrict__ spars_acc)
{
    __shared__ float sv[2624];
    __shared__ int   si[2624];
    int r = blockIdx.x, tid = threadIdx.x;
    const float* row = coeffs + (long long)r * MDICT;
    float vs[8]; int is[8];
#pragma unroll
    for (int j = 0; j < 8; j++) { vs[j] = -FLT_MAX; is[j] = -1; }
    for (int s = 0; s < MDICT / 256; s++) {
        int col = s * 256 + tid;
        ins8(row[col], col, vs, is);
    }
#pragma unroll
    for (int j = 0; j < 8; j++) { sv[tid * 8 + j] = vs[j]; si[tid * 8 + j] = is[j]; }
    __syncthreads();
    if (tid < 64) {
#pragma unroll
        for (int j = 0; j < 8; j++) { vs[j] = -FLT_MAX; is[j] = -1; }
        for (int e = tid * 32; e < tid * 32 + 32; e++) ins8(sv[e], si[e], vs, is);
#pragma unroll
        for (int j = 0; j < 8; j++) { sv[2048 + tid * 8 + j] = vs[j]; si[2048 + tid * 8 + j] = is[j]; }
    }
    __syncthreads();
    if (tid < 8) {
#pragma unroll
        for (int j = 0; j < 8; j++) { vs[j] = -FLT_MAX; is[j] = -1; }
        for (int e = 2048 + tid * 64; e < 2048 + tid * 64 + 64; e++) ins8(sv[e], si[e], vs, is);
#pragma unroll
        for (int j = 0; j < 8; j++) { sv[2560 + tid * 8 + j] = vs[j]; si[2560 + tid * 8 + j] = is[j]; }
    }
    __syncthreads();
    if (tid == 0) {
#pragma unroll
        for (int j = 0; j < 8; j++) { vs[j] = -FLT_MAX; is[j] = -1; }
        for (int e = 2560; e < 2624; e++) ins8(sv[e], si[e], vs, is);
        float s = 0.f;
#pragma unroll
        for (int j = 0; j < 8; j++) {
            tkv[r * 8 + j] = vs[j];
            tki[r * 8 + j] = is[j];
            s += fabsf(vs[j]);
        }
        atomicAdd(spars_acc, s);
    }
}

// -------- x_rec = basis + offset + bias ; norm1 -> normed (bf16) ---------
__global__ __launch_bounds__(256) void xrec_norm_kernel(
    const float* __restrict__ basis, const float* __restrict__ dictw,
    const float* __restrict__ bias, const float* __restrict__ nw,
    const float* __restrict__ tkv, const int* __restrict__ tki,
    unsigned short* __restrict__ normed_bf, float* __restrict__ e_acc)
{
    int r = blockIdx.x, tid = threadIdx.x;
    float vals[8]; int idxs[8];
#pragma unroll
    for (int j = 0; j < 8; j++) { vals[j] = tkv[r * 8 + j]; idxs[j] = tki[r * 8 + j]; }
    long long base = (long long)r * (D / 4) + tid;
    float4 acc = ((const float4*)basis)[base];
    float4 bv = ((const float4*)bias)[tid];
    acc.x += bv.x; acc.y += bv.y; acc.z += bv.z; acc.w += bv.w;
#pragma unroll
    for (int j = 0; j < 8; j++) {
        float4 dv = ((const float4*)dictw)[(long long)idxs[j] * (D / 4) + tid];
        float v = vals[j];
        acc.x += v * dv.x; acc.y += v * dv.y; acc.z += v * dv.z; acc.w += v * dv.w;
    }
    float ss = acc.x * acc.x + acc.y * acc.y + acc.z * acc.z + acc.w * acc.w;
    float tot = blk_sum(ss);
    float rms = sqrtf(tot / (float)D + 1e-6f);
    if (tid == 0) atomicAdd(e_acc, rms);
    float inv = 1.f / rms;
    float4 wv = ((const float4*)nw)[tid];
    uint2 o;
    o.x = (unsigned)f2bf(acc.x * wv.x * inv) | ((unsigned)f2bf(acc.y * wv.y * inv) << 16);
    o.y = (unsigned)f2bf(acc.z * wv.z * inv) | ((unsigned)f2bf(acc.w * wv.w * inv) << 16);
    ((uint2*)normed_bf)[base] = o;
}

// ---------------- rmsnorm2: fp32 in -> bf16 out ----------------
__global__ __launch_bounds__(256) void rmsnorm_kernel(
    const float* __restrict__ xin, const float* __restrict__ nw,
    unsigned short* __restrict__ xout_bf, float* __restrict__ e_acc)
{
    int r = blockIdx.x, tid = threadIdx.x;
    long long base = (long long)r * (D / 4) + tid;
    float4 v = ((const float4*)xin)[base];
    float ss = v.x * v.x + v.y * v.y + v.z * v.z + v.w * v.w;
    float tot = blk_sum(ss);
    float rms = sqrtf(tot / (float)D + 1e-6f);
    if (tid == 0) atomicAdd(e_acc, rms);
    float inv = 1.f / rms;
    float4 wv = ((const float4*)nw)[tid];
    uint2 o;
    o.x = (unsigned)f2bf(v.x * wv.x * inv) | ((unsigned)f2bf(v.y * wv.y * inv) << 16);
    o.y = (unsigned)f2bf(v.z * wv.z * inv) | ((unsigned)f2bf(v.w * wv.w * inv) << 16);
    ((uint2*)xout_bf)[base] = o;
}

// ------- k_mod[z,t,e] = sum_d k_bf[b,t,h*64+d] * rel[h,d,e]  (bf16 out) --
__global__ __launch_bounds__(256) void kmod_kernel(
    const unsigned short* __restrict__ kb, const float* __restrict__ rel,
    unsigned short* __restrict__ kmod_bf)
{
    __shared__ float Rs[64 * 64];
    int z = blockIdx.y;
    int b = z >> 4, h = z & 15;
    int tid = threadIdx.x;
    const float4* r4 = (const float4*)(rel + (long long)h * 4096);
    float4* Rs4 = (float4*)Rs;
#pragma unroll
    for (int i = 0; i < 4; i++) Rs4[tid + 256 * i] = r4[tid + 256 * i];
    __syncthreads();
    int e = tid & 63, tl = tid >> 6;
    int t = blockIdx.x * 4 + tl;
    const unsigned short* krow = kb + ((long long)(b * TT + t)) * D + h * DH;
    float acc = 0.f;
#pragma unroll
    for (int d4 = 0; d4 < 16; d4++) {
        uint2 p = *(const uint2*)&krow[d4 * 4];
        acc += bf2f(p.x & 0xFFFFu) * Rs[(d4 * 4 + 0) * 64 + e];
        acc += bf2f(p.x >> 16)     * Rs[(d4 * 4 + 1) * 64 + e];
        acc += bf2f(p.y & 0xFFFFu) * Rs[(d4 * 4 + 2) * 64 + e];
        acc += bf2f(p.y >> 16)     * Rs[(d4 * 4 + 3) * 64 + e];
    }
    kmod_bf[(long long)z * (TT * DH) + t * 64 + e] = f2bf(acc);
}

// ---- vT[z][d][t] = v_bf[b, t, h*64+d]  (64xTT per z, bf16) --------------
__global__ __launch_bounds__(256) void vtrans_kernel(
    const unsigned short* __restrict__ vb, unsigned short* __restrict__ vT)
{
    __shared__ unsigned short tile[64][68];
    int z = blockIdx.y, b = z >> 4, h = z & 15;
    int t0 = blockIdx.x * 64;
    int tid = threadIdx.x;
    int tr = tid >> 4;
    int dc = (tid & 15) * 4;
#pragma unroll
    for (int r = 0; r < 4; r++) {
        int t = tr + r * 16;
        uint2 p = *(const uint2*)&vb[((long long)(b * TT + t0 + t)) * D + h * DH + dc];
        tile[t][dc] = (unsigned short)(p.x & 0xFFFFu);
        tile[t][dc + 1] = (unsigned short)(p.x >> 16);
        tile[t][dc + 2] = (unsigned short)(p.y & 0xFFFFu);
        tile[t][dc + 3] = (unsigned short)(p.y >> 16);
    }
    __syncthreads();
#pragma unroll
    for (int r = 0; r < 4; r++) {
        int d = tr + r * 16;
        int t = (tid & 15) * 4;
        uint2 p;
        p.x = (unsigned)tile[t][d] | ((unsigned)tile[t + 1][d] << 16);
        p.y = (unsigned)tile[t + 2][d] | ((unsigned)tile[t + 3][d] << 16);
        *(uint2*)&vT[(long long)z * 64 * TT + (long long)d * TT + t0 + t] = p;
    }
}

// ---------------- softmax over rows of attn (width 2048, in place) -------
__global__ __launch_bounds__(256) void softmax_kernel(float* __restrict__ attn)
{
    long long row = blockIdx.x;
    float4* p4 = (float4*)(attn + row * TT);
    int tid = threadIdx.x;
    float4 v0 = p4[tid], v1 = p4[tid + 256];
    float mx = fmaxf(fmaxf(fmaxf(v0.x, v0.y), fmaxf(v0.z, v0.w)),
                     fmaxf(fmaxf(v1.x, v1.y), fmaxf(v1.z, v1.w)));
    mx = blk_max(mx);
    v0.x = __expf(v0.x - mx); v0.y = __expf(v0.y - mx);
    v0.z = __expf(v0.z - mx); v0.w = __expf(v0.w - mx);
    v1.x = __expf(v1.x - mx); v1.y = __expf(v1.y - mx);
    v1.z = __expf(v1.z - mx); v1.w = __expf(v1.w - mx);
    float s = v0.x + v0.y + v0.z + v0.w + v1.x + v1.y + v1.z + v1.w;
    s = blk_sum(s);
    float inv = 1.f / s;
    v0.x *= inv; v0.y *= inv; v0.z *= inv; v0.w *= inv;
    v1.x *= inv; v1.y *= inv; v1.z *= inv; v1.w *= inv;
    p4[tid] = v0; p4[tid + 256] = v1;
}

// ------- h = sigmoid(g) * silu(u), bf16 in, bf16 out in place into g -----
__global__ __launch_bounds__(256) void gateup_kernel(
    unsigned short* __restrict__ g, const unsigned short* __restrict__ u, long long n4)
{
    long long i = (long long)blockIdx.x * 256 + threadIdx.x;
    long long stride = (long long)gridDim.x * 256;
    for (; i < n4; i += stride) {
        uint2 gp = ((uint2*)g)[i];
        uint2 up = ((const uint2*)u)[i];
        float gv[4] = { bf2f(gp.x & 0xFFFFu), bf2f(gp.x >> 16), bf2f(gp.y & 0xFFFFu), bf2f(gp.y >> 16) };
        float uv[4] = { bf2f(up.x & 0xFFFFu), bf2f(up.x >> 16), bf2f(up.y & 0xFFFFu), bf2f(up.y >> 16) };
        unsigned short h[4];
#pragma unroll
        for (int j = 0; j < 4; j++) {
            float r = (1.f / (1.f + __expf(-gv[j]))) * uv[j] * (1.f / (1.f + __expf(-uv[j])));
            h[j] = f2bf(r);
        }
        uint2 o;
        o.x = (unsigned)h[0] | ((unsigned)h[1] << 16);
        o.y = (unsigned)h[2] | ((unsigned)h[3] << 16);
        ((uint2*)g)[i] = o;
    }
}

// ---------------- finalize scalars ----------------
__global__ void finalize_kernel(const float* __restrict__ scal, float* __restrict__ out)
{
    out[OUT_SPARS] = scal[0] / (float)((double)ROWS * (double)MDICT);
    out[OUT_E1] = scal[1] / (float)ROWS;
    out[OUT_E2] = scal[2] / (float)ROWS;
}

extern "C" void kernel_launch(void* const* d_in, const int* in_sizes, int n_in,
                              void* d_out, int out_size, void* d_ws, size_t ws_size,
                              hipStream_t stream) {
    const float* x     = (const float*)d_in[0];
    const float* proto = (const float*)d_in[2];
    const float* fgw   = (const float*)d_in[3];
    const float* dictw = (const float*)d_in[4];
    const float* encw  = (const float*)d_in[5];
    const float* wq    = (const float*)d_in[6];
    const float* wk    = (const float*)d_in[7];
    const float* wv    = (const float*)d_in[8];
    const float* wo    = (const float*)d_in[9];
    const float* rel   = (const float*)d_in[10];
    const float* gatew = (const float*)d_in[11];
    const float* upw   = (const float*)d_in[12];
    const float* downw = (const float*)d_in[13];
    const float* n1w   = (const float*)d_in[14];
    const float* n2w   = (const float*)d_in[15];
    const float* bias  = (const float*)d_in[16];
    float* out = (float*)d_out;
    float* ws  = (float*)d_ws;

    // ---- ws arena (float offsets; bf16 buffers sized n/2 floats) ----
    float*          basisf  = ws + 0;                 // 4.2M fl (also xmid)
    unsigned short* kb_bf   = (unsigned short*)(ws + 4194304);   // 4096x1024
    unsigned short* resid_bf= (unsigned short*)(ws + 6291456);   // also ctx_bf
    unsigned short* norm_bf = (unsigned short*)(ws + 8388608);   // normed / normed2
    unsigned short* qb_bf   = (unsigned short*)(ws + 10485760);
    unsigned short* vb_bf   = (unsigned short*)(ws + 12582912);
    unsigned short* kmod_bf = (unsigned short*)(ws + 14680064);
    unsigned short* vT_bf   = (unsigned short*)(ws + 16777216);
    unsigned short* encw_bf = (unsigned short*)(ws + 18874368);  // also gate_bf (h)
    unsigned short* up_bf   = (unsigned short*)(ws + 27262976);
    unsigned short* wq_bf   = (unsigned short*)(ws + 35651584);
    unsigned short* wk_bf   = (unsigned short*)(ws + 36175872);
    unsigned short* wv_bf   = (unsigned short*)(ws + 36700160);
    unsigned short* wo_bf   = (unsigned short*)(ws + 37224448);
    unsigned short* gatew_bf= (unsigned short*)(ws + 37748736);
    unsigned short* upw_bf  = (unsigned short*)(ws + 39845888);
    unsigned short* downw_bf= (unsigned short*)(ws + 41943040);
    float*          tkv     = ws + 44040192;
    int*            tki     = (int*)(ws + 44072960);
    float*          scal    = ws + 44105728;
    unsigned short* ctx_bf  = resid_bf;
    unsigned short* gate_bf = encw_bf;
    float*          xmid    = basisf;

    float* fs   = out + OUT_FS;
    float* attn = out + OUT_ATTN;
    float* coeffs = attn;            // scratch until attn scores written

    hipMemsetAsync(scal, 0, 3 * sizeof(float), stream);

    // weight conversions (fp32 -> bf16)
    cvt_bf16_kernel<<<2048, 256, 0, stream>>>(encw, encw_bf, (long long)MDICT * D / 4);
    cvt_bf16_kernel<<<256, 256, 0, stream>>>(wq, wq_bf, (long long)D * D / 4);
    cvt_bf16_kernel<<<256, 256, 0, stream>>>(wk, wk_bf, (long long)D * D / 4);
    cvt_bf16_kernel<<<256, 256, 0, stream>>>(wv, wv_bf, (long long)D * D / 4);
    cvt_bf16_kernel<<<256, 256, 0, stream>>>(wo, wo_bf, (long long)D * D / 4);
    cvt_bf16_kernel<<<1024, 256, 0, stream>>>(gatew, gatew_bf, (long long)DFF * D / 4);
    cvt_bf16_kernel<<<1024, 256, 0, stream>>>(upw, upw_bf, (long long)DFF * D / 4);
    cvt_bf16_kernel<<<1024, 256, 0, stream>>>(downw, downw_bf, (long long)D * DFF / 4);

    family_kernel<<<ROWS, 64, 0, stream>>>(x, fgw, fs);
    basis_kernel<<<ROWS, 256, 0, stream>>>(x, fs, proto, basisf, resid_bf);
    // coeffs[4096,16384] = resid @ enc_w^T
    gemm_mfma<128, 128, false, false><<<dim3(128, 32, 1), 256, 0, stream>>>(
        resid_bf, encw_bf, coeffs, nullptr, D, D, D, MDICT, 1.f, 1, 0, 0, 0, 0, 0, 0);
    topk_kernel<<<ROWS, 256, 0, stream>>>(coeffs, tkv, tki, scal + 0);
    xrec_norm_kernel<<<ROWS, 256, 0, stream>>>(basisf, dictw, bias, n1w, tkv, tki, norm_bf, scal + 1);
    // q,k,v [4096,1024] bf16
    gemm_mfma<128, 128, true, false><<<dim3(8, 32, 1), 256, 0, stream>>>(
        norm_bf, wq_bf, qb_bf, nullptr, D, D, D, D, 1.f, 1, 0, 0, 0, 0, 0, 0);
    gemm_mfma<128, 128, true, false><<<dim3(8, 32, 1), 256, 0, stream>>>(
        norm_bf, wk_bf, kb_bf, nullptr, D, D, D, D, 1.f, 1, 0, 0, 0, 0, 0, 0);
    gemm_mfma<128, 128, true, false><<<dim3(8, 32, 1), 256, 0, stream>>>(
        norm_bf, wv_bf, vb_bf, nullptr, D, D, D, D, 1.f, 1, 0, 0, 0, 0, 0, 0);
    kmod_kernel<<<dim3(TT / 4, 32), 256, 0, stream>>>(kb_bf, rel, kmod_bf);
    vtrans_kernel<<<dim3(TT / 64, 32), 256, 0, stream>>>(vb_bf, vT_bf);
    // scores: per (b,h): q[2048,64] @ kmod[2048,64]^T * 0.125 -> attn fp32
    gemm_mfma<128, 128, false, false><<<dim3(16, 16, 32), 256, 0, stream>>>(
        qb_bf, kmod_bf, attn, nullptr, DH, D, DH, TT, 0.125f, NH,
        (long long)TT * D, 64LL,
        (long long)NH * TT * DH, (long long)TT * DH,
        (long long)NH * TT * TT, (long long)TT * TT);
    softmax_kernel<<<32 * TT, 256, 0, stream>>>(attn);
    // ctx = attn(fp32, converted in-kernel) @ vT^T -> ctx_bf
    gemm_mfma<128, 64, true, true><<<dim3(1, 16, 32), 256, 0, stream>>>(
        attn, vT_bf, ctx_bf, nullptr, TT, TT, TT, D, 1.f, NH,
        (long long)NH * TT * TT, (long long)TT * TT,
        (long long)NH * DH * TT, (long long)DH * TT,
        (long long)TT * D, 64LL);
    // xmid = ctx @ wo^T + x  (fp32)
    gemm_mfma<128, 128, false, false><<<dim3(8, 32, 1), 256, 0, stream>>>(
        ctx_bf, wo_bf, xmid, x, D, D, D, D, 1.f, 1, 0, 0, 0, 0, 0, 0);
    rmsnorm_kernel<<<ROWS, 256, 0, stream>>>(xmid, n2w, norm_bf, scal + 2);
    // gate/up [4096,4096] bf16
    gemm_mfma<128, 128, true, false><<<dim3(32, 32, 1), 256, 0, stream>>>(
        norm_bf, gatew_bf, gate_bf, nullptr, D, D, D, DFF, 1.f, 1, 0, 0, 0, 0, 0, 0);
    gemm_mfma<128, 128, true, false><<<dim3(32, 32, 1), 256, 0, stream>>>(
        norm_bf, upw_bf, up_bf, nullptr, D, D, D, DFF, 1.f, 1, 0, 0, 0, 0, 0, 0);
    gateup_kernel<<<4096, 256, 0, stream>>>(gate_bf, up_bf, (long long)ROWS * DFF / 4);
    // out_x = h @ down^T + xmid (fp32)
    gemm_mfma<128, 128, false, false><<<dim3(8, 32, 1), 256, 0, stream>>>(
        gate_bf, downw_bf, out + OUT_X, xmid, DFF, DFF, DFF, D, 1.f, 1, 0, 0, 0, 0, 0, 0);
    finalize_kernel<<<1, 1, 0, stream>>>(scal, out);
}